// Round 19
// baseline (117.898 us; speedup 1.0000x reference)
//
#include <hip/hip_runtime.h>
#include <math.h>

static constexpr int kN = 8192;
static constexpr int kC = 128;
static constexpr int kB = 16;
static constexpr float kScale = 0.5f / 1048576.0f; // 1/(C*N) * 0.5 (pack fold)

#define C8  0.70710678118654752f
#define CP8 0.92387953251128676f
#define SP8 0.38268343236508977f

typedef float v2f __attribute__((ext_vector_type(2)));

__device__ __forceinline__ v2f mk2(float x, float y){ v2f r; r.x=x; r.y=y; return r; }
__device__ __forceinline__ v2f imul(v2f a){ return mk2(-a.y, a.x); }   // +i*a
__device__ __forceinline__ v2f mimul(v2f a){ return mk2(a.y, -a.x); }  // -i*a
__device__ __forceinline__ v2f cconj(v2f a){ return mk2(a.x, -a.y); }
__device__ __forceinline__ v2f cmul(v2f a, v2f b){
    return mk2(a.x*b.x - a.y*b.y, a.x*b.y + a.y*b.x);
}

// e^{+2pi i rev} via HW trans pipe (v_sin/v_cos take REVOLUTIONS).
__device__ __forceinline__ v2f wrev(float rev){
    return mk2(__builtin_amdgcn_cosf(rev), __builtin_amdgcn_sinf(rev));
}

// swizzle (validated r8): conflict-floor for stride-256 / mixed / stride-16.
__device__ __forceinline__ int swz(int n){ return n ^ ((n>>4)&15); }

// slot s = 4j+m holds A[4m+j]; A[k] lives at reg REV(k). REV is an involution.
#define REV(k) ((((k)&3)<<2)|((k)>>2))

template<int SGN>
__device__ __forceinline__ void dft4(v2f&a, v2f&b, v2f&c, v2f&d){
    v2f t0=a+c, t1=a-c, t2=b+d, t3=b-d;
    v2f j3 = (SGN>0) ? imul(t3) : mimul(t3);
    a = t0+t2; b = t1+j3; c = t0-t2; d = t1-j3;
}

// 16-pt DFT; input natural at v[j], output A[k] at v[REV(k)].
template<int SGN>
__device__ __forceinline__ void dft16(v2f* v){
    dft4<SGN>(v[0], v[4], v[8],  v[12]);
    dft4<SGN>(v[1], v[5], v[9],  v[13]);
    dft4<SGN>(v[2], v[6], v[10], v[14]);
    dft4<SGN>(v[3], v[7], v[11], v[15]);
    const float sg = (SGN>0)? 1.f : -1.f;
    const v2f W1 = mk2(CP8,  sg*SP8);
    const v2f W2 = mk2(C8,   sg*C8);
    const v2f W3 = mk2(SP8,  sg*CP8);
    const v2f W6 = mk2(-C8,  sg*C8);
    const v2f W9 = mk2(-CP8, -sg*SP8);
    v[5]  = cmul(v[5],  W1);
    v[9]  = cmul(v[9],  W2);
    v[13] = cmul(v[13], W3);
    v[6]  = cmul(v[6],  W2);
    v[10] = (SGN>0)? imul(v[10]) : mimul(v[10]);
    v[14] = cmul(v[14], W6);
    v[7]  = cmul(v[7],  W3);
    v[11] = cmul(v[11], W6);
    v[15] = cmul(v[15], W9);
    dft4<SGN>(v[0],  v[1],  v[2],  v[3]);
    dft4<SGN>(v[4],  v[5],  v[6],  v[7]);
    dft4<SGN>(v[8],  v[9],  v[10], v[11]);
    dft4<SGN>(v[12], v[13], v[14], v[15]);
}

// Index-renamed dft16 (n -> REV(n) everywhere): input sample j at v[REV(j)],
// output A[m] lands at v[m] (REV involution). Runs stage C' in place, no copy.
template<int SGN>
__device__ __forceinline__ void dft16_rev(v2f* v){
    dft4<SGN>(v[0],  v[1],  v[2],  v[3]);
    dft4<SGN>(v[4],  v[5],  v[6],  v[7]);
    dft4<SGN>(v[8],  v[9],  v[10], v[11]);
    dft4<SGN>(v[12], v[13], v[14], v[15]);
    const float sg = (SGN>0)? 1.f : -1.f;
    const v2f W1 = mk2(CP8,  sg*SP8);
    const v2f W2 = mk2(C8,   sg*C8);
    const v2f W3 = mk2(SP8,  sg*CP8);
    const v2f W6 = mk2(-C8,  sg*C8);
    const v2f W9 = mk2(-CP8, -sg*SP8);
    v[5]  = cmul(v[5],  W1);
    v[6]  = cmul(v[6],  W2);
    v[7]  = cmul(v[7],  W3);
    v[9]  = cmul(v[9],  W2);
    v[10] = (SGN>0)? imul(v[10]) : mimul(v[10]);
    v[11] = cmul(v[11], W6);
    v[13] = cmul(v[13], W3);
    v[14] = cmul(v[14], W6);
    v[15] = cmul(v[15], W9);
    dft4<SGN>(v[0], v[4], v[8],  v[12]);
    dft4<SGN>(v[1], v[5], v[9],  v[13]);
    dft4<SGN>(v[2], v[6], v[10], v[14]);
    dft4<SGN>(v[3], v[7], v[11], v[15]);
}

// DIF twiddle for BOTH rows, powers computed once: A[m] (at REV(m)) *= w1^m
__device__ __forceinline__ void twid_dif2(v2f* a, v2f* b, v2f w1){
    v2f w2=cmul(w1,w1), w3=cmul(w2,w1), w4=cmul(w2,w2);
    v2f w5=cmul(w2,w3), w6=cmul(w3,w3), w7=cmul(w3,w4), w8=cmul(w4,w4);
    v2f w9=cmul(w4,w5), w10=cmul(w5,w5), w11=cmul(w5,w6), w12=cmul(w6,w6);
    v2f w13=cmul(w6,w7), w14=cmul(w7,w7), w15=cmul(w7,w8);
    a[4] =cmul(a[4], w1);  b[4] =cmul(b[4], w1);
    a[8] =cmul(a[8], w2);  b[8] =cmul(b[8], w2);
    a[12]=cmul(a[12],w3);  b[12]=cmul(b[12],w3);
    a[1] =cmul(a[1], w4);  b[1] =cmul(b[1], w4);
    a[5] =cmul(a[5], w5);  b[5] =cmul(b[5], w5);
    a[9] =cmul(a[9], w6);  b[9] =cmul(b[9], w6);
    a[13]=cmul(a[13],w7);  b[13]=cmul(b[13],w7);
    a[2] =cmul(a[2], w8);  b[2] =cmul(b[2], w8);
    a[6] =cmul(a[6], w9);  b[6] =cmul(b[6], w9);
    a[10]=cmul(a[10],w10); b[10]=cmul(b[10],w10);
    a[14]=cmul(a[14],w11); b[14]=cmul(b[14],w11);
    a[3] =cmul(a[3], w12); b[3] =cmul(b[3], w12);
    a[7] =cmul(a[7], w13); b[7] =cmul(b[7], w13);
    a[11]=cmul(a[11],w14); b[11]=cmul(b[11],w14);
    a[15]=cmul(a[15],w15); b[15]=cmul(b[15],w15);
}
// DIT twiddle for BOTH rows (before dft): v[j] *= w1^j, natural index
__device__ __forceinline__ void twid_dit2(v2f* a, v2f* b, v2f w1){
    v2f w2=cmul(w1,w1), w3=cmul(w2,w1), w4=cmul(w2,w2);
    v2f w5=cmul(w2,w3), w6=cmul(w3,w3), w7=cmul(w3,w4), w8=cmul(w4,w4);
    v2f w9=cmul(w4,w5), w10=cmul(w5,w5), w11=cmul(w5,w6), w12=cmul(w6,w6);
    v2f w13=cmul(w6,w7), w14=cmul(w7,w7), w15=cmul(w7,w8);
    a[1] =cmul(a[1], w1);  b[1] =cmul(b[1], w1);
    a[2] =cmul(a[2], w2);  b[2] =cmul(b[2], w2);
    a[3] =cmul(a[3], w3);  b[3] =cmul(b[3], w3);
    a[4] =cmul(a[4], w4);  b[4] =cmul(b[4], w4);
    a[5] =cmul(a[5], w5);  b[5] =cmul(b[5], w5);
    a[6] =cmul(a[6], w6);  b[6] =cmul(b[6], w6);
    a[7] =cmul(a[7], w7);  b[7] =cmul(b[7], w7);
    a[8] =cmul(a[8], w8);  b[8] =cmul(b[8], w8);
    a[9] =cmul(a[9], w9);  b[9] =cmul(b[9], w9);
    a[10]=cmul(a[10],w10); b[10]=cmul(b[10],w10);
    a[11]=cmul(a[11],w11); b[11]=cmul(b[11],w11);
    a[12]=cmul(a[12],w12); b[12]=cmul(b[12],w12);
    a[13]=cmul(a[13],w13); b[13]=cmul(b[13],w13);
    a[14]=cmul(a[14],w14); b[14]=cmul(b[14],w14);
    a[15]=cmul(a[15],w15); b[15]=cmul(b[15],w15);
}

// tanh-form GELU on both components
__device__ __forceinline__ v2f gelu2(v2f v){
    v2f z = v * (0.7978845608028654f + 0.0356774081363001f * v * v);
    float e0 = __builtin_amdgcn_exp2f(-2.8853900817779268f * z.x);
    float e1 = __builtin_amdgcn_exp2f(-2.8853900817779268f * z.y);
    return mk2(v.x / (1.0f + e0), v.y / (1.0f + e1));
}

// Kernel 1: TWO rows per 256-thread WG, radix-16^3, float4-packed LDS
// (row0.re,row0.im,row1.re,row1.im per slot, 64 KiB), Parseval stats,
// 2 full barriers/WG (= 1 per row), wave-local middle, dft16_rev in-place C'.
// (256,2): VGPR cap 128 (bucket law r9-r12); target usage ~110.
__global__ __launch_bounds__(256, 2) void k1_row(
    const float* __restrict__ xr, const float* __restrict__ xi,
    const float* __restrict__ gamma, const float* __restrict__ beta,
    float* __restrict__ outR, float* __restrict__ outI)
{
    __shared__ float4 buf[4096];  // 64 KiB packed row-pair, swizzled
    __shared__ v2f Twb[16];       // W256^q (stage B/B')
    __shared__ v2f sred[4];       // per-wave Parseval partials (row0, row1)

    const int p    = threadIdx.x;        // 0..255
    const int row0 = blockIdx.x * 2;

    if (p < 16) Twb[p] = wrev((float)p * (1.0f/256.0f));
    const int i0 = ((p>>4)<<8) + (p&15);  // stage-B group base

    v2f v0[16], v1[16];

    const float* r0R = xr + (size_t)row0 * kN;
    const float* r0I = xi + (size_t)row0 * kN;
    const float* r1R = r0R + kN;
    const float* r1I = r0I + kN;

    const float mean0 = 2.0f * r0R[0];
    const float mean1 = 2.0f * r1R[0];

    // ---- pre-combine (0.5 dropped; instnorm absorbs): 2*Z[k] + Parseval ----
    float pq0 = 0.f, pq1 = 0.f;
    #pragma unroll
    for (int j = 0; j < 16; ++j) {
        int k   = p + (j<<8);
        int km  = (kN - k) & (kN-1);
        int km2 = 4096 - k;
        v2f w = wrev((float)k * (1.0f/8192.0f));   // e^{+i pi k/4096}, shared
        {
            v2f Hk  = mk2(r0R[k]+r0R[km],       r0I[k]-r0I[km]);
            v2f Hk2 = mk2(r0R[k+4096]+r0R[km2], r0I[k+4096]-r0I[km2]);
            pq0 += Hk.x*Hk.x + Hk.y*Hk.y + Hk2.x*Hk2.x + Hk2.y*Hk2.y;
            v2f S = Hk + Hk2, D = Hk - Hk2;
            v2f P = cmul(D, w);
            v0[j] = S + imul(P);
        }
        {
            v2f Hk  = mk2(r1R[k]+r1R[km],       r1I[k]-r1I[km]);
            v2f Hk2 = mk2(r1R[k+4096]+r1R[km2], r1I[k+4096]-r1I[km2]);
            pq1 += Hk.x*Hk.x + Hk.y*Hk.y + Hk2.x*Hk2.x + Hk2.y*Hk2.y;
            v2f S = Hk + Hk2, D = Hk - Hk2;
            v2f P = cmul(D, w);
            v1[j] = S + imul(P);
        }
    }
    #pragma unroll
    for (int off = 32; off >= 1; off >>= 1) {
        pq0 += __shfl_down(pq0, off);
        pq1 += __shfl_down(pq1, off);
    }
    if ((p & 63) == 0) sred[p>>6] = mk2(pq0, pq1);

    // ---- DIF stage A (h=256), sigma=+1 ----
    dft16<1>(v0); dft16<1>(v1);
    twid_dif2(v0, v1, wrev((float)p * (1.0f/4096.0f)));
    #pragma unroll
    for (int m = 0; m < 16; ++m)
        buf[swz(p + (m<<8))] = make_float4(v0[REV(m)].x, v0[REV(m)].y,
                                           v1[REV(m)].x, v1[REV(m)].y);
    __syncthreads();                      // FULL (1): A->B + Twb + sred

    // ---- stats final (Parseval) ----
    v2f q0 = sred[0], q1 = sred[1], q2 = sred[2], q3 = sred[3];
    float t0 = q0.x + q1.x + q2.x + q3.x;
    float t1 = q0.y + q1.y + q2.y + q3.y;
    const int ch0 = row0 & (kC-1), ch1 = (row0+1) & (kC-1);
    float gg0 = gamma[ch0] * rsqrtf(t0 - mean0*mean0 + 1e-5f);
    float bb0 = beta[ch0] - mean0 * gg0;
    float gg1 = gamma[ch1] * rsqrtf(t1 - mean1*mean1 + 1e-5f);
    float bb1 = beta[ch1] - mean1 * gg1;

    // ==== wave-local region: B | C | norm | C' | B' ====
    const v2f wB = Twb[p & 15];
    #pragma unroll
    for (int j = 0; j < 16; ++j) {
        float4 p4 = buf[swz(i0 + (j<<4))];
        v0[j] = mk2(p4.x, p4.y); v1[j] = mk2(p4.z, p4.w);
    }
    dft16<1>(v0); dft16<1>(v1);
    twid_dif2(v0, v1, wB);
    #pragma unroll
    for (int m = 0; m < 16; ++m)
        buf[swz(i0 + (m<<4))] = make_float4(v0[REV(m)].x, v0[REV(m)].y,
                                            v1[REV(m)].x, v1[REV(m)].y);
    __builtin_amdgcn_wave_barrier();      // B -> C (wave-local)

    #pragma unroll
    for (int j = 0; j < 16; ++j) {
        float4 p4 = buf[swz((p<<4) + j)];
        v0[j] = mk2(p4.x, p4.y); v1[j] = mk2(p4.z, p4.w);
    }
    dft16<1>(v0); dft16<1>(v1);

    // instnorm + GELU (order-agnostic)
    #pragma unroll
    for (int j = 0; j < 16; ++j) {
        v0[j] = gelu2(v0[j] * gg0 + bb0);
        v1[j] = gelu2(v1[j] * gg1 + bb1);
    }

    // DIT stage C' in place: sample j at v[REV(j)] -> dft16_rev -> A[m] at v[m]
    dft16_rev<-1>(v0); dft16_rev<-1>(v1);
    #pragma unroll
    for (int m = 0; m < 16; ++m)
        buf[swz((p<<4) + m)] = make_float4(v0[m].x, v0[m].y, v1[m].x, v1[m].y);
    __builtin_amdgcn_wave_barrier();      // C' -> B' (wave-local)

    #pragma unroll
    for (int j = 0; j < 16; ++j) {
        float4 p4 = buf[swz(i0 + (j<<4))];
        v0[j] = mk2(p4.x, p4.y); v1[j] = mk2(p4.z, p4.w);
    }
    twid_dit2(v0, v1, cconj(wB));
    dft16<-1>(v0); dft16<-1>(v1);
    #pragma unroll
    for (int m = 0; m < 16; ++m)
        buf[swz(i0 + (m<<4))] = make_float4(v0[REV(m)].x, v0[REV(m)].y,
                                            v1[REV(m)].x, v1[REV(m)].y);
    __syncthreads();                      // FULL (2): B' -> A'

    // ---- DIT stage A': Z'[p+256m] at reg REV(m), straight to global ----
    #pragma unroll
    for (int j = 0; j < 16; ++j) {
        float4 p4 = buf[swz(p + (j<<8))];
        v0[j] = mk2(p4.x, p4.y); v1[j] = mk2(p4.z, p4.w);
    }
    twid_dit2(v0, v1, cconj(wrev((float)p * (1.0f/4096.0f))));
    dft16<-1>(v0); dft16<-1>(v1);
    float* o0R = outR + (size_t)row0 * kN;
    float* o0I = outI + (size_t)row0 * kN;
    float* o1R = o0R + kN;
    float* o1I = o0I + kN;
    #pragma unroll
    for (int m = 0; m < 16; ++m) {
        int k = p + (m<<8);
        o0R[k] = v0[REV(m)].x;  o0I[k] = v0[REV(m)].y;
        o1R[k] = v1[REV(m)].x;  o1I[k] = v1[REV(m)].y;
    }
}

// Kernel 2 (r16/r18 verbatim, ~33 us ~= 92% of its HBM floor): per (b, 32-wide
// colA tile): read Z' pair tiles (both contiguous -> full lines), build
// 2*Y[colA] into LDS and 2*Y[4096-colA] into 16 regs, two FFT passes,
// scale + Hermitian-mirror writes in place.
__global__ __launch_bounds__(256, 2) void k2_col(float* __restrict__ outR,
                                                 float* __restrict__ outI)
{
    __shared__ v2f tile[kC][32];  // 32 KiB
    __shared__ v2f tw[64];

    const int tid  = threadIdx.x;
    const int j    = tid & 31;
    const int g    = tid >> 5;        // 0..7
    const int b    = blockIdx.y;
    const int k0   = blockIdx.x << 5; // 0,32,...,2048 (65 blocks)
    const int colA = k0 + j;
    const bool valid = (colA <= 2048);
    const int colB = (4096 - colA) & 4095;

    if (tid < 64) {
        tw[tid] = mk2(__builtin_amdgcn_cosf((float)tid * (1.0f/128.0f)),
                      -__builtin_amdgcn_sinf((float)tid * (1.0f/128.0f)));
    }
    const float wc =  __builtin_amdgcn_cosf((float)colA * (1.0f/8192.0f));
    const float ws = -__builtin_amdgcn_sinf((float)colA * (1.0f/8192.0f));

    float* baseR = outR + (size_t)b * kC * kN;
    float* baseI = outI + (size_t)b * kC * kN;

    v2f yb[16];   // statically indexed (unrolled) -> registers
    #pragma unroll
    for (int ci = 0; ci < 16; ++ci) {
        const int c = g + (ci << 3);
        v2f YA = mk2(0.f, 0.f), YB = mk2(0.f, 0.f);
        if (valid) {
            size_t offA = (size_t)c * kN + colA;
            size_t offB = (size_t)c * kN + colB;
            float Zx  = baseR[offA], Zy  = baseI[offA];
            float Zmx = baseR[offB], Zmy = baseI[offB];
            float Sx = Zx + Zmx, Sy = Zy - Zmy;
            float Dx = Zx - Zmx, Dy = Zy + Zmy;
            float Px = Dx*wc - Dy*ws, Py = Dx*ws + Dy*wc;
            YA = mk2(Sx + Py,  Sy - Px);   // 2*Y[colA]
            YB = mk2(Sx - Py, -Sy - Px);   // 2*Y[4096-colA]
        }
        tile[c][j] = YA;
        yb[ci] = YB;
    }
    __syncthreads();

    // ---- FFT pass A: 128-pt forward DIF along c ----
    for (int st = 7; st >= 1; --st) {
        const int h = 1 << (st-1);
        #pragma unroll
        for (int s = 0; s < 8; ++s) {
            int q   = g + (s<<3);
            int pos = q & (h-1);
            int i0  = ((q >> (st-1)) << st) + pos;
            int i1  = i0 + h;
            v2f a = tile[i0][j], bb = tile[i1][j];
            v2f w = tw[pos << (7-st)];
            tile[i0][j] = a + bb;
            tile[i1][j] = cmul(a - bb, w);
        }
        __syncthreads();
    }
    if (valid) {
        for (int p = g; p < kC; p += 8) {
            int f = (int)(__brev((unsigned)p) >> 25);
            v2f vv = tile[p][j] * kScale;
            size_t off = (size_t)f * kN + colA;
            if (colA == 0) {
                baseR[off] = vv.x; baseI[off] = 0.f;
            } else {
                baseR[off] = vv.x; baseI[off] = vv.y;
                size_t offm = (size_t)f * kN + (kN - colA);
                baseR[offm] = vv.x; baseI[offm] = -vv.y;
            }
        }
    }
    __syncthreads();   // pass-A tile reads done before overwrite

    #pragma unroll
    for (int ci = 0; ci < 16; ++ci) {
        const int c = g + (ci << 3);
        tile[c][j] = yb[ci];
    }
    __syncthreads();

    // ---- FFT pass B ----
    for (int st = 7; st >= 1; --st) {
        const int h = 1 << (st-1);
        #pragma unroll
        for (int s = 0; s < 8; ++s) {
            int q   = g + (s<<3);
            int pos = q & (h-1);
            int i0  = ((q >> (st-1)) << st) + pos;
            int i1  = i0 + h;
            v2f a = tile[i0][j], bb = tile[i1][j];
            v2f w = tw[pos << (7-st)];
            tile[i0][j] = a + bb;
            tile[i1][j] = cmul(a - bb, w);
        }
        __syncthreads();
    }
    if (valid) {
        const int kkB = 4096 - colA;
        for (int p = g; p < kC; p += 8) {
            int f = (int)(__brev((unsigned)p) >> 25);
            v2f vv = tile[p][j] * kScale;
            size_t off = (size_t)f * kN + kkB;
            if (kkB == 4096) {
                baseR[off] = vv.x; baseI[off] = 0.f;
            } else {
                baseR[off] = vv.x; baseI[off] = vv.y;
                size_t offm = (size_t)f * kN + (kN - kkB);
                baseR[offm] = vv.x; baseI[offm] = -vv.y;
            }
        }
    }
}

extern "C" void kernel_launch(void* const* d_in, const int* in_sizes, int n_in,
                              void* d_out, int out_size, void* d_ws, size_t ws_size,
                              hipStream_t stream)
{
    const float* xr    = (const float*)d_in[0];
    const float* xi    = (const float*)d_in[1];
    const float* gamma = (const float*)d_in[2];
    const float* beta  = (const float*)d_in[3];

    float* outR = (float*)d_out;
    float* outI = outR + (size_t)kB * kC * kN;

    k1_row<<<kB * kC / 2, 256, 0, stream>>>(xr, xi, gamma, beta, outR, outI);
    k2_col<<<dim3(65, kB), 256, 0, stream>>>(outR, outI);
}

// Round 20
// 108.183 us; speedup vs baseline: 1.0898x; 1.0898x over previous
//
#include <hip/hip_runtime.h>
#include <math.h>

static constexpr int kN = 8192;
static constexpr int kC = 128;
static constexpr int kB = 16;
static constexpr float kScale = 0.5f / 1048576.0f; // 1/(C*N) * 0.5 (pack fold)

#define C8  0.70710678118654752f
#define CP8 0.92387953251128676f
#define SP8 0.38268343236508977f

typedef float v2f __attribute__((ext_vector_type(2)));

__device__ __forceinline__ v2f mk2(float x, float y){ v2f r; r.x=x; r.y=y; return r; }
__device__ __forceinline__ v2f imul(v2f a){ return mk2(-a.y, a.x); }   // +i*a
__device__ __forceinline__ v2f mimul(v2f a){ return mk2(a.y, -a.x); }  // -i*a
__device__ __forceinline__ v2f cconj(v2f a){ return mk2(a.x, -a.y); }
__device__ __forceinline__ v2f cmul(v2f a, v2f b){
    return mk2(a.x*b.x - a.y*b.y, a.x*b.y + a.y*b.x);
}

// e^{+2pi i rev} via HW trans pipe (v_sin/v_cos take REVOLUTIONS).
__device__ __forceinline__ v2f wrev(float rev){
    return mk2(__builtin_amdgcn_cosf(rev), __builtin_amdgcn_sinf(rev));
}

// swizzle (validated r8): conflict-floor for stride-256 / mixed / stride-16.
// Permutes only within each 256-block -> preserves 1024-block wave-locality.
__device__ __forceinline__ int swz(int n){ return n ^ ((n>>4)&15); }

// slot s = 4j+m holds A[4m+j]; A[k] lives at reg REV(k)
#define REV(k) ((((k)&3)<<2)|((k)>>2))

template<int SGN>
__device__ __forceinline__ void dft4(v2f&a, v2f&b, v2f&c, v2f&d){
    v2f t0=a+c, t1=a-c, t2=b+d, t3=b-d;
    v2f j3 = (SGN>0) ? imul(t3) : mimul(t3);
    a = t0+t2; b = t1+j3; c = t0-t2; d = t1-j3;
}

// 16-pt DFT, A_k = sum_j in[j] e^{SGN*2pi i jk/16}; in natural, out via REV.
template<int SGN>
__device__ __forceinline__ void dft16(v2f* v){
    dft4<SGN>(v[0], v[4], v[8],  v[12]);
    dft4<SGN>(v[1], v[5], v[9],  v[13]);
    dft4<SGN>(v[2], v[6], v[10], v[14]);
    dft4<SGN>(v[3], v[7], v[11], v[15]);
    const float sg = (SGN>0)? 1.f : -1.f;
    const v2f W1 = mk2(CP8,  sg*SP8);
    const v2f W2 = mk2(C8,   sg*C8);
    const v2f W3 = mk2(SP8,  sg*CP8);
    const v2f W6 = mk2(-C8,  sg*C8);
    const v2f W9 = mk2(-CP8, -sg*SP8);
    v[5]  = cmul(v[5],  W1);
    v[9]  = cmul(v[9],  W2);
    v[13] = cmul(v[13], W3);
    v[6]  = cmul(v[6],  W2);
    v[10] = (SGN>0)? imul(v[10]) : mimul(v[10]);
    v[14] = cmul(v[14], W6);
    v[7]  = cmul(v[7],  W3);
    v[11] = cmul(v[11], W6);
    v[15] = cmul(v[15], W9);
    dft4<SGN>(v[0],  v[1],  v[2],  v[3]);
    dft4<SGN>(v[4],  v[5],  v[6],  v[7]);
    dft4<SGN>(v[8],  v[9],  v[10], v[11]);
    dft4<SGN>(v[12], v[13], v[14], v[15]);
}

// DIF stage twiddle: A[m] (at reg REV(m)) *= w1^m, m=1..15
__device__ __forceinline__ void twid_dif(v2f* v, v2f w1){
    v2f w2=cmul(w1,w1), w3=cmul(w2,w1), w4=cmul(w2,w2);
    v2f w5=cmul(w2,w3), w6=cmul(w3,w3), w7=cmul(w3,w4), w8=cmul(w4,w4);
    v2f w9=cmul(w4,w5), w10=cmul(w5,w5), w11=cmul(w5,w6), w12=cmul(w6,w6);
    v2f w13=cmul(w6,w7), w14=cmul(w7,w7), w15=cmul(w7,w8);
    v[4] =cmul(v[4], w1);  v[8] =cmul(v[8], w2);  v[12]=cmul(v[12],w3);
    v[1] =cmul(v[1], w4);  v[5] =cmul(v[5], w5);  v[9] =cmul(v[9], w6);
    v[13]=cmul(v[13],w7);  v[2] =cmul(v[2], w8);  v[6] =cmul(v[6], w9);
    v[10]=cmul(v[10],w10); v[14]=cmul(v[14],w11); v[3] =cmul(v[3], w12);
    v[7] =cmul(v[7], w13); v[11]=cmul(v[11],w14); v[15]=cmul(v[15],w15);
}
// DIT stage twiddle (before dft): v[j] *= w1^j, natural index
__device__ __forceinline__ void twid_dit(v2f* v, v2f w1){
    v2f w2=cmul(w1,w1), w3=cmul(w2,w1), w4=cmul(w2,w2);
    v2f w5=cmul(w2,w3), w6=cmul(w3,w3), w7=cmul(w3,w4), w8=cmul(w4,w4);
    v2f w9=cmul(w4,w5), w10=cmul(w5,w5), w11=cmul(w5,w6), w12=cmul(w6,w6);
    v2f w13=cmul(w6,w7), w14=cmul(w7,w7), w15=cmul(w7,w8);
    v[1] =cmul(v[1], w1);  v[2] =cmul(v[2], w2);  v[3] =cmul(v[3], w3);
    v[4] =cmul(v[4], w4);  v[5] =cmul(v[5], w5);  v[6] =cmul(v[6], w6);
    v[7] =cmul(v[7], w7);  v[8] =cmul(v[8], w8);  v[9] =cmul(v[9], w9);
    v[10]=cmul(v[10],w10); v[11]=cmul(v[11],w11); v[12]=cmul(v[12],w12);
    v[13]=cmul(v[13],w13); v[14]=cmul(v[14],w14); v[15]=cmul(v[15],w15);
}

// tanh-form GELU on both components
__device__ __forceinline__ v2f gelu2(v2f v){
    v2f z = v * (0.7978845608028654f + 0.0356774081363001f * v * v);
    float e0 = __builtin_amdgcn_exp2f(-2.8853900817779268f * z.x);
    float e1 = __builtin_amdgcn_exp2f(-2.8853900817779268f * z.y);
    return mk2(v.x / (1.0f + e0), v.y / (1.0f + e1));
}

// Kernel 1 (session-best, ~75.6 us): one row per 256-thread WG, radix-16^3,
// Parseval stats (mean = 2*xr[0], E[x^2] from pre-combine), 2 full barriers
// + wave-local middle, trans-pipe twiddles, 32 KiB swizzled LDS, 4 WG/CU.
__global__ __launch_bounds__(256, 4) void k1_row(
    const float* __restrict__ xr, const float* __restrict__ xi,
    const float* __restrict__ gamma, const float* __restrict__ beta,
    float* __restrict__ outR, float* __restrict__ outI)
{
    __shared__ v2f buf[4096];   // 32 KiB, swizzled
    __shared__ v2f Twb[16];     // W256^q (stage B/B')
    __shared__ float sred[4];   // per-wave Parseval partials

    const int p   = threadIdx.x;        // 0..255
    const int row = blockIdx.x;
    const int ch  = row & (kC-1);

    if (p < 16) Twb[p] = wrev((float)p * (1.0f/256.0f));
    const int i0 = ((p>>4)<<8) + (p&15);  // stage-B group base

    v2f v[16];

    const float* rR = xr + (size_t)row * kN;
    const float* rI = xi + (size_t)row * kN;

    const float mean = 2.0f * rR[0];      // Sum x / N = H~[0] = 2*Re X[0]

    // ---- pre-combine (0.5 dropped; instnorm absorbs): 2*Z[k] + Parseval ----
    float pq = 0.f;
    #pragma unroll
    for (int j = 0; j < 16; ++j) {
        int k   = p + (j<<8);
        int km  = (kN - k) & (kN-1);
        int km2 = 4096 - k;
        v2f w = wrev((float)k * (1.0f/8192.0f));   // e^{+i pi k/4096}
        v2f Hk  = mk2(rR[k]+rR[km],       rI[k]-rI[km]);
        v2f Hk2 = mk2(rR[k+4096]+rR[km2], rI[k+4096]-rI[km2]);
        pq += Hk.x*Hk.x + Hk.y*Hk.y + Hk2.x*Hk2.x + Hk2.y*Hk2.y;
        v2f S = Hk + Hk2, D = Hk - Hk2;
        v2f P = cmul(D, w);
        v[j] = S + imul(P);
    }
    // wave-reduce Parseval partial; leader writes its slot (pre-barrier)
    #pragma unroll
    for (int off = 32; off >= 1; off >>= 1)
        pq += __shfl_down(pq, off);
    if ((p & 63) == 0) sred[p>>6] = pq;

    // ---- DIF stage A (h=256), sigma=+1; w1 = W4096^p via trans pipe ----
    dft16<1>(v);
    twid_dif(v, wrev((float)p * (1.0f/4096.0f)));
    #pragma unroll
    for (int m = 0; m < 16; ++m) buf[swz(p + (m<<8))] = v[REV(m)];
    __syncthreads();                      // FULL (1): A->B + Twb + sred ready

    // ---- stats final (hoisted; E[x^2] = Parseval total) ----
    float total = sred[0] + sred[1] + sred[2] + sred[3];
    float var  = total - mean*mean;
    float gg = gamma[ch] * rsqrtf(var + 1e-5f);
    float bb = beta[ch] - mean * gg;

    // ==== wave-local region: B | C | norm | C' | B' ====
    const v2f wB = Twb[p & 15];
    #pragma unroll
    for (int j = 0; j < 16; ++j) v[j] = buf[swz(i0 + (j<<4))];
    dft16<1>(v);
    twid_dif(v, wB);
    #pragma unroll
    for (int m = 0; m < 16; ++m) buf[swz(i0 + (m<<4))] = v[REV(m)];
    __builtin_amdgcn_wave_barrier();      // B -> C (wave-local)

    #pragma unroll
    for (int j = 0; j < 16; ++j) v[j] = buf[swz((p<<4) + j)];
    dft16<1>(v);

    // instnorm + GELU (order-agnostic), straight-line
    #pragma unroll
    for (int j = 0; j < 16; ++j) v[j] = gelu2(v[j] * gg + bb);

    // DIT stage C' (h=1): sample at slot 16p+j is v[REV(j)]
    {
        v2f u[16];
        #pragma unroll
        for (int j = 0; j < 16; ++j) u[j] = v[REV(j)];
        dft16<-1>(u);
        #pragma unroll
        for (int m = 0; m < 16; ++m) buf[swz((p<<4) + m)] = u[REV(m)];
    }
    __builtin_amdgcn_wave_barrier();      // C' -> B' (wave-local)

    #pragma unroll
    for (int j = 0; j < 16; ++j) v[j] = buf[swz(i0 + (j<<4))];
    twid_dit(v, cconj(wB));
    dft16<-1>(v);
    #pragma unroll
    for (int m = 0; m < 16; ++m) buf[swz(i0 + (m<<4))] = v[REV(m)];
    __syncthreads();                      // FULL (2): B' -> A'

    // ---- DIT stage A': Z'[p+256m] at reg REV(m), straight to global ----
    #pragma unroll
    for (int j = 0; j < 16; ++j) v[j] = buf[swz(p + (j<<8))];
    twid_dit(v, cconj(wrev((float)p * (1.0f/4096.0f))));
    dft16<-1>(v);
    float* oR = outR + (size_t)row * kN;
    float* oI = outI + (size_t)row * kN;
    #pragma unroll
    for (int m = 0; m < 16; ++m) {
        int k = p + (m<<8);
        oR[k] = v[REV(m)].x;
        oI[k] = v[REV(m)].y;
    }
}

// Kernel 2 (session-best, ~33 us ~= 92% of its HBM floor): per (b, 32-wide
// colA tile): read Z' pair tiles (both contiguous -> full lines), build
// 2*Y[colA] into LDS and 2*Y[4096-colA] into 16 regs, two FFT passes,
// scale + Hermitian-mirror writes in place.
__global__ __launch_bounds__(256, 2) void k2_col(float* __restrict__ outR,
                                                 float* __restrict__ outI)
{
    __shared__ v2f tile[kC][32];  // 32 KiB
    __shared__ v2f tw[64];

    const int tid  = threadIdx.x;
    const int j    = tid & 31;
    const int g    = tid >> 5;        // 0..7
    const int b    = blockIdx.y;
    const int k0   = blockIdx.x << 5; // 0,32,...,2048 (65 blocks)
    const int colA = k0 + j;
    const bool valid = (colA <= 2048);
    const int colB = (4096 - colA) & 4095;

    if (tid < 64) {
        tw[tid] = mk2(__builtin_amdgcn_cosf((float)tid * (1.0f/128.0f)),
                      -__builtin_amdgcn_sinf((float)tid * (1.0f/128.0f)));
    }
    const float wc =  __builtin_amdgcn_cosf((float)colA * (1.0f/8192.0f));
    const float ws = -__builtin_amdgcn_sinf((float)colA * (1.0f/8192.0f));

    float* baseR = outR + (size_t)b * kC * kN;
    float* baseI = outI + (size_t)b * kC * kN;

    v2f yb[16];   // statically indexed (unrolled) -> registers
    #pragma unroll
    for (int ci = 0; ci < 16; ++ci) {
        const int c = g + (ci << 3);
        v2f YA = mk2(0.f, 0.f), YB = mk2(0.f, 0.f);
        if (valid) {
            size_t offA = (size_t)c * kN + colA;
            size_t offB = (size_t)c * kN + colB;
            float Zx  = baseR[offA], Zy  = baseI[offA];
            float Zmx = baseR[offB], Zmy = baseI[offB];
            float Sx = Zx + Zmx, Sy = Zy - Zmy;
            float Dx = Zx - Zmx, Dy = Zy + Zmy;
            float Px = Dx*wc - Dy*ws, Py = Dx*ws + Dy*wc;
            YA = mk2(Sx + Py,  Sy - Px);   // 2*Y[colA]
            YB = mk2(Sx - Py, -Sy - Px);   // 2*Y[4096-colA]
        }
        tile[c][j] = YA;
        yb[ci] = YB;
    }
    __syncthreads();

    // ---- FFT pass A: 128-pt forward DIF along c ----
    for (int st = 7; st >= 1; --st) {
        const int h = 1 << (st-1);
        #pragma unroll
        for (int s = 0; s < 8; ++s) {
            int q   = g + (s<<3);
            int pos = q & (h-1);
            int i0  = ((q >> (st-1)) << st) + pos;
            int i1  = i0 + h;
            v2f a = tile[i0][j], bb = tile[i1][j];
            v2f w = tw[pos << (7-st)];
            tile[i0][j] = a + bb;
            tile[i1][j] = cmul(a - bb, w);
        }
        __syncthreads();
    }
    if (valid) {
        for (int p = g; p < kC; p += 8) {
            int f = (int)(__brev((unsigned)p) >> 25);
            v2f vv = tile[p][j] * kScale;
            size_t off = (size_t)f * kN + colA;
            if (colA == 0) {
                baseR[off] = vv.x; baseI[off] = 0.f;
            } else {
                baseR[off] = vv.x; baseI[off] = vv.y;
                size_t offm = (size_t)f * kN + (kN - colA);
                baseR[offm] = vv.x; baseI[offm] = -vv.y;
            }
        }
    }
    __syncthreads();   // pass-A tile reads done before overwrite

    #pragma unroll
    for (int ci = 0; ci < 16; ++ci) {
        const int c = g + (ci << 3);
        tile[c][j] = yb[ci];
    }
    __syncthreads();

    // ---- FFT pass B ----
    for (int st = 7; st >= 1; --st) {
        const int h = 1 << (st-1);
        #pragma unroll
        for (int s = 0; s < 8; ++s) {
            int q   = g + (s<<3);
            int pos = q & (h-1);
            int i0  = ((q >> (st-1)) << st) + pos;
            int i1  = i0 + h;
            v2f a = tile[i0][j], bb = tile[i1][j];
            v2f w = tw[pos << (7-st)];
            tile[i0][j] = a + bb;
            tile[i1][j] = cmul(a - bb, w);
        }
        __syncthreads();
    }
    if (valid) {
        const int kkB = 4096 - colA;
        for (int p = g; p < kC; p += 8) {
            int f = (int)(__brev((unsigned)p) >> 25);
            v2f vv = tile[p][j] * kScale;
            size_t off = (size_t)f * kN + kkB;
            if (kkB == 4096) {
                baseR[off] = vv.x; baseI[off] = 0.f;
            } else {
                baseR[off] = vv.x; baseI[off] = vv.y;
                size_t offm = (size_t)f * kN + (kN - kkB);
                baseR[offm] = vv.x; baseI[offm] = -vv.y;
            }
        }
    }
}

extern "C" void kernel_launch(void* const* d_in, const int* in_sizes, int n_in,
                              void* d_out, int out_size, void* d_ws, size_t ws_size,
                              hipStream_t stream)
{
    const float* xr    = (const float*)d_in[0];
    const float* xi    = (const float*)d_in[1];
    const float* gamma = (const float*)d_in[2];
    const float* beta  = (const float*)d_in[3];

    float* outR = (float*)d_out;
    float* outI = outR + (size_t)kB * kC * kN;

    k1_row<<<kB * kC, 256, 0, stream>>>(xr, xi, gamma, beta, outR, outI);
    k2_col<<<dim3(65, kB), 256, 0, stream>>>(outR, outI);
}